// Round 8
// baseline (158.544 us; speedup 1.0000x reference)
//
#include <hip/hip_runtime.h>

#define H 360
#define W 720
#define NB 8
#define XC 3
#define YC 10
#define TX 240
#define TY 36
#define BPB (XC*YC)             // 30 blocks per batch
#define WR 52                   // window rows: gi = by-8+r, r in 0..51
#define LST 260                 // LDS row stride (floats): 256 cols + 4 pad
#define LSZ (WR*LST)            // one window buffer (floats)
#define DTS 600.0f
#define REARTH 6371000.0f
#define D2R 0.017453292519943295f

#define NQ1 (WR*64)             // 3328 preamble quads
#define NHALO 1168              // rows{0..7,44..51}x64 + rows 8..43 x quads{0,1,62,63}
#define NGROUPS 5               // 5 groups x 4 substeps = 20 steps
#define FLAG_STRIDE 32          // 128 B per flag line

// Round 8: OWN-ROWS-IN-REGISTERS. Phase-alternation model: per substep, all
// 16 waves burst LDS reads (DS serializes, VALU starved), then compute (DS
// idle) -> phases ADD (~20us DS + ~33us VALU + ~13us sync = 67us observed).
// Fix: each wave's 3 own rows live in registers across substeps (they were
// being written to LDS and re-read by the same wave). Reads 7->4 (neighbor
// boundary rows only); writes stay 3 (neighbors consume all 3). Center h row
// (own-rows-only) computes first, covering the 4 reads' latency. Register
// refresh from LDS after halo imports for col-edge lanes (the only lanes
// whose own-row values the import changes).

// LLC-coherent 8B load/store (agent-scope relaxed atomic -> dwordx2 sc1)
static __device__ __forceinline__ float2 ldc8(const float* p) {
    unsigned long long u = __hip_atomic_load((const unsigned long long*)p,
                                             __ATOMIC_RELAXED, __HIP_MEMORY_SCOPE_AGENT);
    return __builtin_bit_cast(float2, u);
}
static __device__ __forceinline__ void stc8(float* p, float2 v) {
    __hip_atomic_store((unsigned long long*)p, __builtin_bit_cast(unsigned long long, v),
                       __ATOMIC_RELAXED, __HIP_MEMORY_SCOPE_AGENT);
}

// DPP wave-wide lane shifts on the VALU pipe (bound_ctrl=1: shifted-in lanes
// read 0 — lands only in window cols 0/255, the unconsumed degraded halo).
static __device__ __forceinline__ float dpp_up1(float x) {   // lane i <- lane i-1
    return __builtin_bit_cast(float, __builtin_amdgcn_update_dpp(
        0, __builtin_bit_cast(int, x), 0x138 /*wave_shr:1*/, 0xF, 0xF, true));
}
static __device__ __forceinline__ float dpp_dn1(float x) {   // lane i <- lane i+1
    return __builtin_bit_cast(float, __builtin_amdgcn_update_dpp(
        0, __builtin_bit_cast(int, x), 0x130 /*wave_shl:1*/, 0xF, 0xF, true));
}

__global__ __launch_bounds__(1024, 1) void ocean_persist(
    const float* __restrict__ Tin, const float* __restrict__ ug,
    const float* __restrict__ vg, const float* __restrict__ lat,
    const float* __restrict__ lon, const float* __restrict__ mask,
    float* __restrict__ out, float* __restrict__ wsf, int* __restrict__ flags)
{
    // Double-buffered window: substep reads buf p, writes buf p^1 ->
    // one barrier per substep. 108 KB LDS, 1 block/CU (grid caps residency).
    __shared__ float sT[2 * LSZ];

    const int tid = threadIdx.x;
    const int b  = blockIdx.z;
    const int bx = blockIdx.x * TX;
    const int by = blockIdx.y * TY;
    const int plane = H * W;

    const float dlat = lat[1] - lat[0];               // -0.5
    const float dy   = REARTH * D2R * fabsf(dlat);
    const float sgn  = (dlat > 0.f) ? 1.f : -1.f;
    const float dlon = lon[1] - lon[0];
    const float i2dy = 0.5f / dy, i1dy = 1.f / dy;

    const float* Tb = Tin + b * plane;
    const float* ub = ug  + b * plane;
    const float* vb = vg  + b * plane;
    float* outb = out + b * plane;
    float* wsb  = wsf + b * plane;

    int* bflags = flags + b * BPB * FLAG_STRIDE;
    int* myflag = bflags + (blockIdx.y * XC + blockIdx.x) * FLAG_STRIDE;

    // ---------- strip mapping: 16 waves x 3-row output pitch ----------
    const int cq = tid & 63;             // col quad 0..63 (window cols 0..255)
    const int rg = tid >> 6;             // row group 0..15 (== wave id)
    const int c0 = cq << 2;
    const int a  = 1 + 3 * rg;           // first h row; h rows a..a+4 (j<5)
    const int gj0 = (bx - 8 + c0 + W) % W;
    const bool hlzb = (gj0 == 0);            // filter zero-pad left of gj=0
    const bool hrzb = (gj0 + 3 == W - 1);    // filter zero-pad right of gj=W-1

    // ---------- bake invariants ----------
    int goff1[4], lds1o[4];              // preamble quads (1024-thread stride)
    #pragma unroll
    for (int k = 0; k < 4; ++k) {
        const int q = tid + 1024 * k;
        if (q < NQ1) {
            const int r = q >> 6, cc0 = (q & 63) << 2;
            const int gi = min(max(by - 8 + r, 0), H - 1);
            const int gj = (bx - 8 + cc0 + W) % W;
            goff1[k] = gi * W + gj;
            lds1o[k] = r * LST + cc0;
        } else goff1[k] = -1;
    }

    int hgo[2], hlo[2];                  // halo import quads (2/thread)
    #pragma unroll
    for (int t = 0; t < 2; ++t) {
        const int q = tid + 1024 * t;
        if (q < NHALO) {
            int r, cc0;
            if (q < 1024) { const int ri = q >> 6; r = (ri < 8) ? ri : 36 + ri; cc0 = (q & 63) << 2; }
            else { const int u = q - 1024; r = 8 + (u >> 2); const int qi = u & 3;
                   cc0 = (qi < 2) ? (qi << 2) : (248 + ((qi - 2) << 2)); }
            const int gi = min(max(by - 8 + r, 0), H - 1);
            const int gj = (bx - 8 + cc0 + W) % W;
            hgo[t] = gi * W + gj;
            hlo[t] = r * LST + cc0;
        } else hgo[t] = -1;
    }

    // advection coeffs for own 5 h rows (wrapped gj -> halo cols evolve truly)
    float cuA[5][4], cvA[5][4];
    unsigned domm = 0, topm = 0, botm = 0;
    #pragma unroll
    for (int j = 0; j < 5; ++j) {
        #pragma unroll
        for (int t = 0; t < 4; ++t) { cuA[j][t] = 0.f; cvA[j][t] = 0.f; }
        const int gi = by - 8 + a + j;
        if ((unsigned)gi < H) {
            const float dxv  = REARTH * D2R * dlon * cosf(lat[gi] * D2R);
            const float rdx2 = 0.5f / dxv;
            const float ivy  = (gi == 0 || gi == H - 1) ? i1dy : i2dy;
            #pragma unroll
            for (int t = 0; t < 4; ++t) {
                const int off = gi * W + gj0 + t;
                const float mk = mask[off];
                cuA[j][t] = -DTS * mk * ub[off] * rdx2;
                cvA[j][t] = -DTS * mk * vb[off] * sgn * ivy;
            }
            domm |= 1u << j;
            if (gi == 0)     topm |= 1u << j;   // one-sided: row above := self
            if (gi == H - 1) botm |= 1u << j;   // one-sided: row below := self
        }
    }

    // out rows n = 2+3rg+i, i = 0..2; m16 as 12-bit mask (mask/16 = bit*0.0625)
    unsigned mb = 0, outm = 0, tilem = 0, ringm = 0;
    int o3A[3];
    #pragma unroll
    for (int i = 0; i < 3; ++i) {
        const int n = 2 + 3 * rg + i;
        const int gi = by - 8 + n;
        o3A[i] = 0;
        #pragma unroll
        for (int t = 0; t < 4; ++t)
            if ((unsigned)gi < H && mask[gi * W + gj0 + t] != 0.f) mb |= 1u << (4 * i + t);
        if ((unsigned)gi < H) outm |= 1u << i;    // write sT (in-domain rows only)
        const bool inTile = (n >= 8 && n <= 43 && cq >= 2 && cq <= 61);
        if (inTile) {
            o3A[i] = gi * W + bx + c0 - 8;
            tilem |= 1u << i;
            if (n <= 15 || n >= 36 || cq <= 3 || cq >= 60) ringm |= 1u << i;
        }
    }
    const int rbase = 3 * rg * LST + c0;           // LDS read base (row n0-2)
    const int wbase = (2 + 3 * rg) * LST + c0;     // LDS write base (row n0)

    // neighbor flag pointers (8-neighborhood; x wraps, y clamps to self)
    const int* nbrF = myflag;
    if (tid < 8) {
        int dyn, dxn;
        if (tid < 3)      { dyn = -1; dxn = tid - 1; }
        else if (tid == 3){ dyn = 0;  dxn = -1; }
        else if (tid == 4){ dyn = 0;  dxn = 1; }
        else              { dyn = 1;  dxn = tid - 6; }
        const int ny = (int)blockIdx.y + dyn;
        const int nx = ((int)blockIdx.x + dxn + XC) % XC;
        if (ny >= 0 && ny < YC) nbrF = bflags + (ny * XC + nx) * FLAG_STRIDE;
    }

    // ---------- preamble: full window -> BOTH buffers ----------
    // (buf1's never-rewritten rows 0,1,50,51 hold finite preamble values;
    //  they feed only domm-zeroed h rows / replica-overridden derivatives.)
    #pragma unroll
    for (int k = 0; k < 4; ++k)
        if (goff1[k] >= 0) {
            const float4 v = *(const float4*)(Tb + goff1[k]);
            *(float4*)(sT + lds1o[k])       = v;
            *(float4*)(sT + LSZ + lds1o[k]) = v;
        }
    __syncthreads();

    // ---------- own 3 rows live in registers across substeps ----------
    float4 tA0 = *(const float4*)(sT + wbase);             // row n0
    float4 tA1 = *(const float4*)(sT + wbase + LST);       // row n0+1
    float4 tA2 = *(const float4*)(sT + wbase + 2 * LST);   // row n0+2

    // advect + horizontal filter for coeff row j (compile-time j)
    auto Hrow = [&](int j, const float4& m1, const float4& cc, const float4& vD) -> float4 {
        const float4 m1e = ((topm >> j) & 1) ? cc : m1;
        const float4 vDe = ((botm >> j) & 1) ? cc : vD;
        const float tl = dpp_up1(cc.w);    // 0 only at cq=0 -> col 0 (unconsumed)
        const float tr = dpp_dn1(cc.x);    // 0 only at cq=63 -> col 255
        const bool dj = (domm >> j) & 1;
        float4 o;
        o.x = (dj ? cc.x : 0.f) + cuA[j][0]*(cc.y - tl)   + cvA[j][0]*(vDe.x - m1e.x);
        o.y = (dj ? cc.y : 0.f) + cuA[j][1]*(cc.z - cc.x) + cvA[j][1]*(vDe.y - m1e.y);
        o.z = (dj ? cc.z : 0.f) + cuA[j][2]*(cc.w - cc.y) + cvA[j][2]*(vDe.z - m1e.z);
        o.w = (dj ? cc.w : 0.f) + cuA[j][3]*(tr   - cc.z) + cvA[j][3]*(vDe.w - m1e.w);
        float hl = dpp_up1(o.w);
        float hr = dpp_dn1(o.x);
        if (hlzb) hl = 0.f;
        if (hrzb) hr = 0.f;
        float4 r;
        r.x = hl  + 2.f * o.x + o.y;
        r.y = o.x + 2.f * o.y + o.z;
        r.z = o.y + 2.f * o.z + o.w;
        r.w = o.z + 2.f * o.w + hr;
        return r;
    };

    // ---------- one substep: 4 neighbor reads, 3 writes, ONE barrier ----------
    auto substep = [&](int p, bool finalOut, float* ring) {
        const float* cur = sT + p * LSZ;
        float* nxt = sT + (p ^ 1) * LSZ;
        // neighbor boundary rows (issued first; compiler waits at first use)
        const float4 rU2 = *(const float4*)(cur + rbase);              // row n0-2
        const float4 rU1 = *(const float4*)(cur + rbase + LST);        // row n0-1
        const float4 rD1 = *(const float4*)(cur + rbase + 5 * LST);    // row n0+3
        const float4 rD2 = *(const float4*)(cur + rbase + 6 * LST);    // row n0+4
        float4 hA[5];
        hA[2] = Hrow(2, tA0, tA1, tA2);   // own-only: covers read latency
        hA[1] = Hrow(1, rU1, tA0, tA1);
        hA[0] = Hrow(0, rU2, rU1, tA0);
        hA[3] = Hrow(3, tA1, tA2, rD1);
        hA[4] = Hrow(4, tA2, rD1, rD2);
        // stage 2: vertical filter + mask; update register rows with outputs
        #pragma unroll
        for (int i = 0; i < 3; ++i) {
            const float4 hm = hA[i], hc = hA[i + 1], hp = hA[i + 2];
            float4 ov;
            const float sx = hm.x + 2.f * hc.x + hp.x;
            const float sy = hm.y + 2.f * hc.y + hp.y;
            const float sz = hm.z + 2.f * hc.z + hp.z;
            const float sw = hm.w + 2.f * hc.w + hp.w;
            ov.x = ((mb >> (4 * i + 0)) & 1) ? sx * 0.0625f : 0.f;
            ov.y = ((mb >> (4 * i + 1)) & 1) ? sy * 0.0625f : 0.f;
            ov.z = ((mb >> (4 * i + 2)) & 1) ? sz * 0.0625f : 0.f;
            ov.w = ((mb >> (4 * i + 3)) & 1) ? sw * 0.0625f : 0.f;
            if (!finalOut) {
                if ((outm >> i) & 1)
                    *(float4*)(nxt + wbase + i * LST) = ov;
            } else if ((tilem >> i) & 1) {
                *(float4*)(outb + o3A[i]) = ov;
            }
            if (ring && ((ringm >> i) & 1)) {
                float2 lo; lo.x = ov.x; lo.y = ov.y;
                float2 hi; hi.x = ov.z; hi.y = ov.w;
                stc8(ring + o3A[i], lo);
                stc8(ring + o3A[i] + 2, hi);
            }
            if (i == 0) tA0 = ov;
            else if (i == 1) tA1 = ov;
            else tA2 = ov;
        }
        __syncthreads();
    };

    // ---------- 5 groups x 4 substeps ----------
    // Parity: substeps read 0,1,0,1 -> group always ends with data in buf0,
    // and the halo import always lands in buf0.
    #pragma unroll 1
    for (int g = 0; g < NGROUPS; ++g) {
        if (g) {
            __syncthreads();   // drains ring stores (per-wave vmcnt0 before s_barrier)
            if (tid == 0)
                __hip_atomic_store(myflag, g, __ATOMIC_RELAXED, __HIP_MEMORY_SCOPE_AGENT);
            if (tid < 64) {    // wave 0, lanes 0..7 poll the 8 neighbors
                long long t0c = (long long)clock64();
                for (;;) {
                    const int v = (tid < 8)
                        ? __hip_atomic_load(nbrF, __ATOMIC_RELAXED, __HIP_MEMORY_SCOPE_AGENT)
                        : 0x7fffffff;
                    if (__all(v >= g)) break;
                    __builtin_amdgcn_s_sleep(1);
                    if ((long long)clock64() - t0c > 200000000LL) break;  // no-hang bailout
                }
            }
            __syncthreads();
            // halo import (depth 8) from ring(g-1): g-1 even -> outb, odd -> wsb
            const float* prev = ((g - 1) & 1) ? wsb : outb;
            #pragma unroll
            for (int t = 0; t < 2; ++t) {
                if (hgo[t] >= 0) {
                    const float2 lo = ldc8(prev + hgo[t]);
                    const float2 hi = ldc8(prev + hgo[t] + 2);
                    float4 v; v.x = lo.x; v.y = lo.y; v.z = hi.x; v.w = hi.y;
                    *(float4*)(sT + hlo[t]) = v;   // buf0 = current data buffer
                }
            }
            __syncthreads();
            // refresh register rows where the import changed own-row values:
            // col-edge lanes (quads 0,1,62,63). Row-band import rows are
            // out-of-domain (outm=0) -> register copies there are dead.
            if (cq < 2 || cq >= 62) {
                tA0 = *(const float4*)(sT + wbase);
                tA1 = *(const float4*)(sT + wbase + LST);
                tA2 = *(const float4*)(sT + wbase + 2 * LST);
            }
        }
        const bool lastG = (g == NGROUPS - 1);
        float* ringp = lastG ? nullptr : ((g & 1) ? wsb : outb);   // ring(g)
        substep(0, false, nullptr);
        substep(1, false, nullptr);
        substep(0, false, nullptr);
        substep(1, lastG, ringp);            // 4th substep: export ring / final tile
    }
}

extern "C" void kernel_launch(void* const* d_in, const int* in_sizes, int n_in,
                              void* d_out, int out_size, void* d_ws, size_t ws_size,
                              hipStream_t stream)
{
    const float* T    = (const float*)d_in[0];
    const float* ug   = (const float*)d_in[1];
    const float* vg   = (const float*)d_in[2];
    const float* lat  = (const float*)d_in[3];
    const float* lon  = (const float*)d_in[4];
    const float* mask = (const float*)d_in[5];
    float* out = (float*)d_out;

    int*   flags = (int*)d_ws;                        // 8 x 30 flags @ 128 B
    float* wsf   = (float*)((char*)d_ws + 65536);     // odd-group ring buffer

    hipMemsetAsync(d_ws, 0, 65536, stream);

    ocean_persist<<<dim3(XC, YC, NB), dim3(1024), 0, stream>>>(
        T, ug, vg, lat, lon, mask, out, wsf, flags);
}

// Round 9
// 136.589 us; speedup vs baseline: 1.1607x; 1.1607x over previous
//
#include <hip/hip_runtime.h>

#define H 360
#define W 720
#define NB 8
#define XC 3
#define YC 10
#define TX 240
#define TY 36
#define BPB (XC*YC)             // 30 blocks per batch
#define WR 52                   // window rows: gi = by-8+r, r in 0..51
#define LST 260                 // LDS row stride (floats): 256 cols + 4 pad
#define LSZ (WR*LST)            // one window buffer (floats)
#define DTS 600.0f
#define REARTH 6371000.0f
#define D2R 0.017453292519943295f

#define NQ1 (WR*64)             // 3328 preamble quads
#define NHALO 1168              // rows{0..7,44..51}x64 + rows 8..43 x quads{0,1,62,63}
#define NGROUPS 5               // 5 groups x 4 substeps = 20 steps
#define FLAG_STRIDE 32          // 128 B per flag line

// Round 9 (FINAL): revert to the empirically best variant (R2: 66.2-67.4 us
// /dispatch, absmax 6.1e-5). Nine structural experiments (barrier halving,
// DPP shifts, 2x occupancy, step fusion, half-tiles, deep halo, spill diet,
// interior fast path, own-rows-in-reg) pinned this geometry's band at
// 66-71 us; all geometry departures were 1.5-3x worse. Floor is a
// distributed latency chain: 20 barrier convoys (DS burst + dep chain +
// drain ~2.5us each) + 4 LLC sync rounds, with HBM at 16%, VALU at 47%,
// conflicts sub-us — no counter saturated, no marginal cut visible.

// LLC-coherent 8B load/store (agent-scope relaxed atomic -> dwordx2 sc1)
static __device__ __forceinline__ float2 ldc8(const float* p) {
    unsigned long long u = __hip_atomic_load((const unsigned long long*)p,
                                             __ATOMIC_RELAXED, __HIP_MEMORY_SCOPE_AGENT);
    return __builtin_bit_cast(float2, u);
}
static __device__ __forceinline__ void stc8(float* p, float2 v) {
    __hip_atomic_store((unsigned long long*)p, __builtin_bit_cast(unsigned long long, v),
                       __ATOMIC_RELAXED, __HIP_MEMORY_SCOPE_AGENT);
}

// DPP wave-wide lane shifts on the VALU pipe (bound_ctrl=1: shifted-in lanes
// read 0 — lands only in window cols 0/255, the unconsumed degraded halo).
static __device__ __forceinline__ float dpp_up1(float x) {   // lane i <- lane i-1
    return __builtin_bit_cast(float, __builtin_amdgcn_update_dpp(
        0, __builtin_bit_cast(int, x), 0x138 /*wave_shr:1*/, 0xF, 0xF, true));
}
static __device__ __forceinline__ float dpp_dn1(float x) {   // lane i <- lane i+1
    return __builtin_bit_cast(float, __builtin_amdgcn_update_dpp(
        0, __builtin_bit_cast(int, x), 0x130 /*wave_shl:1*/, 0xF, 0xF, true));
}

__global__ __launch_bounds__(1024, 4) void ocean_persist(
    const float* __restrict__ Tin, const float* __restrict__ ug,
    const float* __restrict__ vg, const float* __restrict__ lat,
    const float* __restrict__ lon, const float* __restrict__ mask,
    float* __restrict__ out, float* __restrict__ wsf, int* __restrict__ flags)
{
    // Double-buffered window: stage1 reads buf p, stage2 writes buf p^1 ->
    // one barrier per substep. 108 KB LDS, 1 block/CU (grid caps residency).
    __shared__ float sT[2 * LSZ];

    const int tid = threadIdx.x;
    const int b  = blockIdx.z;
    const int bx = blockIdx.x * TX;
    const int by = blockIdx.y * TY;
    const int plane = H * W;

    const float dlat = lat[1] - lat[0];               // -0.5
    const float dy   = REARTH * D2R * fabsf(dlat);
    const float sgn  = (dlat > 0.f) ? 1.f : -1.f;
    const float dlon = lon[1] - lon[0];
    const float i2dy = 0.5f / dy, i1dy = 1.f / dy;

    const float* Tb = Tin + b * plane;
    const float* ub = ug  + b * plane;
    const float* vb = vg  + b * plane;
    float* outb = out + b * plane;
    float* wsb  = wsf + b * plane;

    int* bflags = flags + b * BPB * FLAG_STRIDE;
    int* myflag = bflags + (blockIdx.y * XC + blockIdx.x) * FLAG_STRIDE;

    // ---------- strip mapping: wave = 3-row group ----------
    const int cq = tid & 63;             // col quad 0..63 (window cols 0..255)
    const int rg = tid >> 6;             // row group 0..15 (== wave id)
    const int c0 = cq << 2;
    const int a  = 1 + 3 * rg;           // first h row; h rows a..a+4 (j<5)
    const int gj0 = (bx - 8 + c0 + W) % W;
    const bool hlzb = (gj0 == 0);            // filter zero-pad left of gj=0
    const bool hrzb = (gj0 + 3 == W - 1);    // filter zero-pad right of gj=W-1
    const bool topB = (blockIdx.y == 0), botB = (blockIdx.y == YC - 1);

    // ---------- bake invariants ----------
    int goff1[4], lds1o[4];              // preamble quads (1024-thread stride)
    #pragma unroll
    for (int k = 0; k < 4; ++k) {
        const int q = tid + 1024 * k;
        if (q < NQ1) {
            const int r = q >> 6, cc0 = (q & 63) << 2;
            int gi = by - 8 + r; gi = min(max(gi, 0), H - 1);
            const int gj = (bx - 8 + cc0 + W) % W;
            goff1[k] = gi * W + gj;
            lds1o[k] = r * LST + cc0;
        } else goff1[k] = -1;
    }

    int hgo[2], hlo[2];                  // halo import quads (2/thread)
    #pragma unroll
    for (int t = 0; t < 2; ++t) {
        const int q = tid + 1024 * t;
        if (q < NHALO) {
            int r, cc0;
            if (q < 1024) { const int ri = q >> 6; r = (ri < 8) ? ri : 36 + ri; cc0 = (q & 63) << 2; }
            else { const int u = q - 1024; r = 8 + (u >> 2); const int qi = u & 3;
                   cc0 = (qi < 2) ? (qi << 2) : (248 + ((qi - 2) << 2)); }
            int gi = by - 8 + r; gi = min(max(gi, 0), H - 1);
            const int gj = (bx - 8 + cc0 + W) % W;
            hgo[t] = gi * W + gj;
            hlo[t] = r * LST + cc0;
        } else hgo[t] = -1;
    }

    // advection coeffs for own 5 h rows (wrapped gj -> halo cols evolve truly)
    float cuA[5][4], cvA[5][4];
    unsigned domm = 0;
    #pragma unroll
    for (int j = 0; j < 5; ++j) {
        #pragma unroll
        for (int t = 0; t < 4; ++t) { cuA[j][t] = 0.f; cvA[j][t] = 0.f; }
        const int gi = by - 8 + a + j;
        if ((unsigned)gi < H) {
            const float dxv  = REARTH * D2R * dlon * cosf(lat[gi] * D2R);
            const float rdx2 = 0.5f / dxv;
            const float ivy  = (gi == 0 || gi == H - 1) ? i1dy : i2dy;
            #pragma unroll
            for (int t = 0; t < 4; ++t) {
                const int off = gi * W + gj0 + t;
                const float mk = mask[off];
                cuA[j][t] = -DTS * mk * ub[off] * rdx2;
                cvA[j][t] = -DTS * mk * vb[off] * sgn * ivy;
            }
            domm |= 1u << j;
        }
    }

    // out rows n = 2+3rg+i, i = 0..2
    float m16A[3][4];
    int o3A[3];
    unsigned outm = 0, tilem = 0, ringm = 0;
    #pragma unroll
    for (int i = 0; i < 3; ++i) {
        const int n = 2 + 3 * rg + i;
        const int gi = by - 8 + n;
        o3A[i] = 0;
        #pragma unroll
        for (int t = 0; t < 4; ++t)
            m16A[i][t] = ((unsigned)gi < H) ? mask[gi * W + gj0 + t] * (1.f / 16.f) : 0.f;
        if ((unsigned)gi < H) outm |= 1u << i;    // write sT (in-domain rows only)
        const bool inTile = (n >= 8 && n <= 43 && cq >= 2 && cq <= 61);
        if (inTile) {
            o3A[i] = gi * W + bx + c0 - 8;
            tilem |= 1u << i;
            if (n <= 15 || n >= 36 || cq <= 3 || cq >= 60) ringm |= 1u << i;
        }
    }

    // neighbor flag pointers (8-neighborhood; x wraps, y clamps to self)
    const int* nbrF = myflag;
    if (tid < 8) {
        int dyn, dxn;
        if (tid < 3)      { dyn = -1; dxn = tid - 1; }
        else if (tid == 3){ dyn = 0;  dxn = -1; }
        else if (tid == 4){ dyn = 0;  dxn = 1; }
        else              { dyn = 1;  dxn = tid - 6; }
        const int ny = (int)blockIdx.y + dyn;
        const int nx = ((int)blockIdx.x + dxn + XC) % XC;
        if (ny >= 0 && ny < YC) nbrF = bflags + (ny * XC + nx) * FLAG_STRIDE;
    }

    // ---------- preamble: full window -> BOTH buffers ----------
    // (buf1's never-rewritten halo rows 0,1,50,51 must hold finite values;
    //  they are only ever consumed into the degraded-validity region.)
    #pragma unroll
    for (int k = 0; k < 4; ++k)
        if (goff1[k] >= 0) {
            const float4 v = *(const float4*)(Tb + goff1[k]);
            *(float4*)(sT + lds1o[k])       = v;
            *(float4*)(sT + LSZ + lds1o[k]) = v;
        }
    __syncthreads();

    // ---------- one substep: read buf p, write buf p^1, ONE barrier ----------
    auto substep = [&](int p, bool finalOut, float* ring) {
        const float* cur = sT + p * LSZ;
        float* nxt = sT + (p ^ 1) * LSZ;
        float4 hA[5];
        float4 m1 = *(const float4*)(cur + (a - 1) * LST + c0);
        float4 cc = *(const float4*)(cur + a * LST + c0);
        #pragma unroll
        for (int j = 0; j < 5; ++j) {
            const float4 vD = *(const float4*)(cur + (a + j + 1) * LST + c0);
            const float tl = dpp_up1(cc.w);    // 0 only at cq=0 -> col 0 (unconsumed)
            const float tr = dpp_dn1(cc.x);    // 0 only at cq=63 -> col 255
            const bool dj = (domm >> j) & 1;
            float4 o;
            o.x = (dj ? cc.x : 0.f) + cuA[j][0]*(cc.y - tl)   + cvA[j][0]*(vD.x - m1.x);
            o.y = (dj ? cc.y : 0.f) + cuA[j][1]*(cc.z - cc.x) + cvA[j][1]*(vD.y - m1.y);
            o.z = (dj ? cc.z : 0.f) + cuA[j][2]*(cc.w - cc.y) + cvA[j][2]*(vD.z - m1.z);
            o.w = (dj ? cc.w : 0.f) + cuA[j][3]*(tr   - cc.z) + cvA[j][3]*(vD.w - m1.w);
            float hl = dpp_up1(o.w);
            float hr = dpp_dn1(o.x);
            if (hlzb) hl = 0.f;
            if (hrzb) hr = 0.f;
            hA[j].x = hl  + 2.f * o.x + o.y;
            hA[j].y = o.x + 2.f * o.y + o.z;
            hA[j].z = o.y + 2.f * o.z + o.w;
            hA[j].w = o.z + 2.f * o.w + hr;
            m1 = cc; cc = vD;
        }
        // no mid-substep barrier: stage2 writes the OTHER buffer
        #pragma unroll
        for (int i = 0; i < 3; ++i) {
            const float4 hm = hA[i], hc = hA[i + 1], hp = hA[i + 2];
            float4 o;
            o.x = (hm.x + 2.f * hc.x + hp.x) * m16A[i][0];
            o.y = (hm.y + 2.f * hc.y + hp.y) * m16A[i][1];
            o.z = (hm.z + 2.f * hc.z + hp.z) * m16A[i][2];
            o.w = (hm.w + 2.f * hc.w + hp.w) * m16A[i][3];
            if (!finalOut) {
                if ((outm >> i) & 1)
                    *(float4*)(nxt + (2 + 3 * rg + i) * LST + c0) = o;
                // clamp-replica patches (unique writers: edge rows suppressed above)
                if (topB && rg == 2  && i == 0) *(float4*)(nxt + 7  * LST + c0) = o;  // row7 <- n=8
                if (botB && rg == 13 && i == 2) *(float4*)(nxt + 44 * LST + c0) = o;  // row44 <- n=43
            } else if ((tilem >> i) & 1) {
                *(float4*)(outb + o3A[i]) = o;
            }
            if (ring && ((ringm >> i) & 1)) {
                float2 lo; lo.x = o.x; lo.y = o.y;
                float2 hi; hi.x = o.z; hi.y = o.w;
                stc8(ring + o3A[i], lo);
                stc8(ring + o3A[i] + 2, hi);
            }
        }
        __syncthreads();
    };

    // ---------- 5 groups x 4 substeps ----------
    // Parity: substeps read 0,1,0,1 -> group always ends with data in buf0,
    // and the halo import always lands in buf0.
    #pragma unroll 1
    for (int g = 0; g < NGROUPS; ++g) {
        if (g) {
            __syncthreads();   // drains ring stores (per-wave vmcnt0 before s_barrier)
            if (tid == 0)
                __hip_atomic_store(myflag, g, __ATOMIC_RELAXED, __HIP_MEMORY_SCOPE_AGENT);
            if (tid < 64) {    // wave 0, lanes 0..7 poll the 8 neighbors
                long long t0 = (long long)clock64();
                for (;;) {
                    const int v = (tid < 8)
                        ? __hip_atomic_load(nbrF, __ATOMIC_RELAXED, __HIP_MEMORY_SCOPE_AGENT)
                        : 0x7fffffff;
                    if (__all(v >= g)) break;
                    __builtin_amdgcn_s_sleep(1);
                    if ((long long)clock64() - t0 > 200000000LL) break;  // no-hang bailout
                }
            }
            __syncthreads();
            // halo import (depth 8) from ring(g-1): g-1 even -> outb, odd -> wsb
            const float* prev = ((g - 1) & 1) ? wsb : outb;
            #pragma unroll
            for (int t = 0; t < 2; ++t) {
                if (hgo[t] >= 0) {
                    const float2 lo = ldc8(prev + hgo[t]);
                    const float2 hi = ldc8(prev + hgo[t] + 2);
                    float4 v; v.x = lo.x; v.y = lo.y; v.z = hi.x; v.w = hi.y;
                    *(float4*)(sT + hlo[t]) = v;   // buf0 = current data buffer
                }
            }
            __syncthreads();
        }
        const bool lastG = (g == NGROUPS - 1);
        float* ring = lastG ? nullptr : ((g & 1) ? wsb : outb);   // ring(g)
        substep(0, false, nullptr);
        substep(1, false, nullptr);
        substep(0, false, nullptr);
        substep(1, lastG, ring);            // 4th substep: export ring / final tile
    }
}

extern "C" void kernel_launch(void* const* d_in, const int* in_sizes, int n_in,
                              void* d_out, int out_size, void* d_ws, size_t ws_size,
                              hipStream_t stream)
{
    const float* T    = (const float*)d_in[0];
    const float* ug   = (const float*)d_in[1];
    const float* vg   = (const float*)d_in[2];
    const float* lat  = (const float*)d_in[3];
    const float* lon  = (const float*)d_in[4];
    const float* mask = (const float*)d_in[5];
    float* out = (float*)d_out;

    int*   flags = (int*)d_ws;                        // 8 x 30 flags @ 128 B
    float* wsf   = (float*)((char*)d_ws + 65536);     // odd-group ring buffer

    hipMemsetAsync(d_ws, 0, 65536, stream);

    ocean_persist<<<dim3(XC, YC, NB), dim3(1024), 0, stream>>>(
        T, ug, vg, lat, lon, mask, out, wsf, flags);
}